// Round 5
// baseline (665.070 us; speedup 1.0000x reference)
//
#include <hip/hip_runtime.h>
#include <hip/hip_bf16.h>
#include <math.h>

#define B_N 32
#define S_LEN 4096
#define NTOK (B_N * S_LEN)   // 131072
#define EMB 256
#define NCODE 512
#define WB_STRIDE 98304      // per-batch weight entries (bf16)
#define CBLD 264             // padded codebook row (ushorts); 16*264*2 = 8448 B/chunk

typedef __attribute__((ext_vector_type(8))) short short8v;   // 8 bf16 = 4 VGPRs
typedef __attribute__((ext_vector_type(4))) float float4v;

__device__ inline ushort f2b(float v) {
    union { __hip_bfloat16 h; ushort u; } cv;
    cv.h = __float2bfloat16(v);   // RNE
    return cv.u;
}
__device__ inline float b2f(ushort u) {
    union { ushort u2[2]; float f; } cv;
    cv.u2[0] = 0; cv.u2[1] = u;
    return cv.f;
}
__device__ inline short8v pack8(float4 a, float4 b) {
    short8v r;
    r[0] = (short)f2b(a.x); r[1] = (short)f2b(a.y);
    r[2] = (short)f2b(a.z); r[3] = (short)f2b(a.w);
    r[4] = (short)f2b(b.x); r[5] = (short)f2b(b.y);
    r[6] = (short)f2b(b.z); r[7] = (short)f2b(b.w);
    return r;
}

// ---- ws layout (bytes) ----
constexpr size_t WSB_W   = 0;         // ushort[3145728] generated weights (bf16)
constexpr size_t WSB_CB  = 6291456;   // ushort[512*264] padded codebook bf16 (270336 B)
constexpr size_t WSB_CBN = 6562048;   // float[512] codebook sq-norms
constexpr size_t WSB_ACC = 6564096;   // float[513]: [0]=sse, [1..512]=hist

// ---- out layout (floats) ----
constexpr size_t OUT_SCAL = 33554432; // loss, perplexity
constexpr size_t OUT_XR   = 33554434; // x_recon fp32

// ================= prep: MFMA weight-gen + codebook prep =================
// W[b][R] = bw[R] + ab[R] + (adapt[b] . aw[R])   as bf16
// GEMM: M=32 batches, N=98304 rows, K=64.  Blocks 0..383: weights (4 waves x
// 64 rows each).  Blocks 384..385: codebook norms + padded bf16 copy.
struct WgenP {
    const float* bw[6]; const float* aw[6]; const float* ab[6];
    int loff[6];
};

__global__ __launch_bounds__(256)
void prep_kernel(WgenP p, const float* __restrict__ adapt, ushort* __restrict__ wout,
                 const float* __restrict__ cb, float* __restrict__ cbn,
                 ushort* __restrict__ cbbf)
{
    const int tid = threadIdx.x;
    if (blockIdx.x >= 384) {   // codebook: fp32 norms + padded bf16 copy
        int c = (blockIdx.x - 384) * 256 + tid;
        const float4* c4 = reinterpret_cast<const float4*>(cb) + (size_t)c * 64;
        float s = 0.f;
#pragma unroll 8
        for (int q = 0; q < 64; ++q) {
            float4 v = c4[q];
            s += v.x*v.x + v.y*v.y + v.z*v.z + v.w*v.w;
            *reinterpret_cast<ushort4*>(cbbf + (size_t)c * CBLD + 4*q) =
                make_ushort4(f2b(v.x), f2b(v.y), f2b(v.z), f2b(v.w));
        }
        cbn[c] = s;
        return;
    }
    const int lane = tid & 63, w = tid >> 6;
    const int r16 = lane & 15, g = lane >> 4;

    // A-frags: adapt [32][64] fp32 -> bf16; lane holds batch=mt*16+r16, k=kf*32+g*8
    short8v A[2][2];
#pragma unroll
    for (int mt = 0; mt < 2; ++mt)
#pragma unroll
        for (int kf = 0; kf < 2; ++kf) {
            const float4* pa = reinterpret_cast<const float4*>(
                adapt + (size_t)(mt*16 + r16) * 64 + kf*32 + g*8);
            A[mt][kf] = pack8(pa[0], pa[1]);
        }

    const int R0 = (blockIdx.x * 4 + w) * 64;
#pragma unroll 1
    for (int t = 0; t < 4; ++t) {
        const int R = R0 + t * 16;
        int l = 0;
        if (R >= 8192)  l = 1;
        if (R >= 16384) l = 2;
        if (R >= 49152) l = 3;
        if (R >= 81920) l = 4;
        if (R >= 90112) l = 5;
        const int rl = R - p.loff[l];
        // B-frags: aw rows (n=r16)
        short8v Bf[2];
#pragma unroll
        for (int kf = 0; kf < 2; ++kf) {
            const float4* pb = reinterpret_cast<const float4*>(
                p.aw[l] + (size_t)(rl + r16) * 64 + kf*32 + g*8);
            Bf[kf] = pack8(pb[0], pb[1]);
        }
        float base = p.bw[l][rl + r16] + p.ab[l][rl + r16];
#pragma unroll
        for (int mt = 0; mt < 2; ++mt) {
            float4v acc = (float4v){0.f, 0.f, 0.f, 0.f};
            acc = __builtin_amdgcn_mfma_f32_16x16x32_bf16(A[mt][0], Bf[0], acc, 0, 0, 0);
            acc = __builtin_amdgcn_mfma_f32_16x16x32_bf16(A[mt][1], Bf[1], acc, 0, 0, 0);
#pragma unroll
            for (int reg = 0; reg < 4; ++reg) {
                int batch = mt*16 + g*4 + reg;
                wout[(size_t)batch * WB_STRIDE + R + r16] = f2b(acc[reg] + base);
            }
        }
    }
}

// ================= helpers for the fused kernel =================
template<int KF>
__device__ __forceinline__ void read_afrags(const ushort* lds, int stride,
                                            int r16, int g, short8v (&a)[2][KF])
{
#pragma unroll
    for (int mt = 0; mt < 2; ++mt)
#pragma unroll
        for (int kf = 0; kf < KF; ++kf)
            a[mt][kf] = *reinterpret_cast<const short8v*>(
                lds + (mt*16 + r16) * stride + kf*32 + g*8);
}

// dense layer: OUT = act(A @ W^T + b); A frags in regs, W from global (dbuf),
// result bf16 -> LDS (layout-transform for next layer's A-frags).
template<int KF, int ACT>
__device__ __forceinline__ void dense_layer(const ushort* __restrict__ wsrc,
                                            const float* __restrict__ bias, int NT,
                                            const short8v (&a)[2][KF],
                                            ushort* dlds, int dstride,
                                            int r16, int g)
{
    constexpr int K = KF * 32;
    short8v cur[KF], nxt[KF];
    const ushort* wrow = wsrc + (size_t)r16 * K + g*8;
#pragma unroll
    for (int kf = 0; kf < KF; ++kf)
        cur[kf] = *reinterpret_cast<const short8v*>(wrow + kf*32);
    float bc = bias[r16];
#pragma unroll 1
    for (int nt = 0; nt < NT; ++nt) {
        float bn = 0.f;
        if (nt + 1 < NT) {
            const ushort* wn = wrow + (size_t)(nt + 1) * 16 * K;
#pragma unroll
            for (int kf = 0; kf < KF; ++kf)
                nxt[kf] = *reinterpret_cast<const short8v*>(wn + kf*32);
            bn = bias[(nt + 1) * 16 + r16];
        }
#pragma unroll
        for (int mt = 0; mt < 2; ++mt) {
            float4v acc = (float4v){0.f, 0.f, 0.f, 0.f};
#pragma unroll
            for (int kf = 0; kf < KF; ++kf)
                acc = __builtin_amdgcn_mfma_f32_16x16x32_bf16(a[mt][kf], cur[kf], acc, 0, 0, 0);
#pragma unroll
            for (int reg = 0; reg < 4; ++reg) {
                float v = acc[reg] + bc;
                if (ACT == 1) v = fmaxf(v, 0.f);
                dlds[(mt*16 + g*4 + reg) * dstride + nt*16 + r16] = f2b(v);
            }
        }
#pragma unroll
        for (int kf = 0; kf < KF; ++kf) cur[kf] = nxt[kf];
        bc = bn;
    }
}

// stage one 16-code padded chunk (8448 B) into LDS, fire-and-forget (9 insts)
__device__ __forceinline__ void stage_chunk(const ushort* __restrict__ cbbf,
                                            int ct, char* buf, int lane)
{
    const char* gp = reinterpret_cast<const char*>(cbbf) + (size_t)ct * 8448;
#pragma unroll
    for (int i = 0; i < 8; ++i)
        __builtin_amdgcn_global_load_lds(
            (const __attribute__((address_space(1))) void*)(gp + i*1024 + lane*16),
            (__attribute__((address_space(3))) void*)(buf + i*1024), 16, 0, 0);
    __builtin_amdgcn_global_load_lds(
        (const __attribute__((address_space(1))) void*)(gp + 8192 + lane*4),
        (__attribute__((address_space(3))) void*)(buf + 8192), 4, 0, 0);
}

// ================= fully fused VQ-VAE: one wave per block, 32 tokens =================
// Rolled loops (i-cache), register-dbuf weights, global_load_lds-dbuf codebook.
// LDS 33920 B -> 4 blocks/CU.
__global__ __launch_bounds__(64)
void vqvae_fused(const float* __restrict__ x, const ushort* __restrict__ wbf,
                 const float* __restrict__ bb0, const float* __restrict__ bb1,
                 const float* __restrict__ bb2, const float* __restrict__ bb3,
                 const float* __restrict__ bb4, const float* __restrict__ bb5,
                 const ushort* __restrict__ cbbf, const float* __restrict__ cbf,
                 const float* __restrict__ cbn,
                 float* __restrict__ zq, float* __restrict__ xr,
                 float* __restrict__ accg)
{
    __shared__ __align__(16) char smem[33920];
    // Region1 @0 (16896 B): h0@0 (4608) + h1@4608 (8704) ; then cb0@0/cb1@8448 ;
    //                       then h3@0 (8704) + h4@8704 (4608)
    // Region2 @16896 (16896 B): zb [32][264] bf16
    // midx @33792 (128 B)
    ushort* h0  = reinterpret_cast<ushort*>(smem);
    ushort* h1  = reinterpret_cast<ushort*>(smem + 4608);
    char*   cb0 = smem;
    char*   cb1 = smem + 8448;
    ushort* h3  = reinterpret_cast<ushort*>(smem);
    ushort* h4  = reinterpret_cast<ushort*>(smem + 8704);
    ushort* zb  = reinterpret_cast<ushort*>(smem + 16896);
    int*   midx = reinterpret_cast<int*>(smem + 33792);

    const int lane = threadIdx.x;
    const int r16 = lane & 15, g = lane >> 4;
    // XCD swizzle: 8 XCDs round-robin on blockIdx -> give each XCD 4 batches
    const int gtile = (blockIdx.x & 7) * 512 + (blockIdx.x >> 3);
    const size_t tb = (size_t)gtile * 32;
    const int b = gtile >> 7;
    const ushort* wb = wbf + (size_t)b * WB_STRIDE;

    // ---- stage x A-frags (fp32 -> bf16)
    short8v ax[2][4];
#pragma unroll
    for (int mt = 0; mt < 2; ++mt)
#pragma unroll
        for (int ks = 0; ks < 4; ++ks) {
            const float4* p4 = reinterpret_cast<const float4*>(
                x + (tb + mt*16 + r16) * 128 + ks*32 + g*8);
            ax[mt][ks] = pack8(p4[0], p4[1]);
        }

    // ---- encoder
    dense_layer<4, 1>(wb,          bb0, 4,  ax, h0, 72,  r16, g);   // e0 128->64
    short8v a1[2][2];
    read_afrags<2>(h0, 72, r16, g, a1);
    dense_layer<2, 1>(wb + 8192,   bb1, 8,  a1, h1, 136, r16, g);   // e1 64->128
    short8v a2[2][4];
    read_afrags<4>(h1, 136, r16, g, a2);
    dense_layer<4, 0>(wb + 16384,  bb2, 16, a2, zb, CBLD, r16, g);  // e2 128->256

    // ---- VQ: argmin over dist' = ||e||^2 - 2*(z.e)
    short8v az[2][8];
    read_afrags<8>(zb, CBLD, r16, g, az);

    float mv[2][4] = {{1e30f,1e30f,1e30f,1e30f},{1e30f,1e30f,1e30f,1e30f}};
    int   mi[2][4] = {{0,0,0,0},{0,0,0,0}};

    stage_chunk(cbbf, 0, cb0, lane);
    float cn_c = cbn[r16];
#pragma unroll 1
    for (int ct = 0; ct < 32; ++ct) {
        char* bufc = (ct & 1) ? cb1 : cb0;
        char* bufn = (ct & 1) ? cb0 : cb1;
        stage_chunk(cbbf, (ct < 31) ? ct + 1 : 0, bufn, lane);  // ct=31: dummy keeps count
        float cn_n = (ct < 31) ? cbn[(ct + 1) * 16 + r16] : 0.f;
        __builtin_amdgcn_s_waitcnt(0xF79);   // vmcnt(9): chunk ct resident
        const ushort* cbl = reinterpret_cast<const ushort*>(bufc);
        float4v d0a = (float4v){0.f,0.f,0.f,0.f}, d0b = d0a, d1a = d0a, d1b = d0a;
#pragma unroll
        for (int ks = 0; ks < 4; ++ks) {
            short8v f0 = *reinterpret_cast<const short8v*>(&cbl[r16*CBLD + ks*32 + g*8]);
            short8v f1 = *reinterpret_cast<const short8v*>(&cbl[r16*CBLD + (ks+4)*32 + g*8]);
            d0a = __builtin_amdgcn_mfma_f32_16x16x32_bf16(az[0][ks],   f0, d0a, 0, 0, 0);
            d0b = __builtin_amdgcn_mfma_f32_16x16x32_bf16(az[0][ks+4], f1, d0b, 0, 0, 0);
            d1a = __builtin_amdgcn_mfma_f32_16x16x32_bf16(az[1][ks],   f0, d1a, 0, 0, 0);
            d1b = __builtin_amdgcn_mfma_f32_16x16x32_bf16(az[1][ks+4], f1, d1b, 0, 0, 0);
        }
        int c = ct*16 + r16;
#pragma unroll
        for (int reg = 0; reg < 4; ++reg) {
            float dd0 = cn_c - 2.0f * (d0a[reg] + d0b[reg]);
            if (dd0 < mv[0][reg]) { mv[0][reg] = dd0; mi[0][reg] = c; }
            float dd1 = cn_c - 2.0f * (d1a[reg] + d1b[reg]);
            if (dd1 < mv[1][reg]) { mv[1][reg] = dd1; mi[1][reg] = c; }
        }
        cn_c = cn_n;
    }
    __builtin_amdgcn_s_waitcnt(0xF70);   // drain dummy before Region1 reuse

    // butterfly over 16 code-lanes; lex (val, idx) min == first-index argmin
#pragma unroll
    for (int m = 1; m <= 8; m <<= 1) {
#pragma unroll
        for (int mt = 0; mt < 2; ++mt)
#pragma unroll
            for (int reg = 0; reg < 4; ++reg) {
                float ov = __shfl_xor(mv[mt][reg], m);
                int   oi = __shfl_xor(mi[mt][reg], m);
                if (ov < mv[mt][reg] || (ov == mv[mt][reg] && oi < mi[mt][reg])) {
                    mv[mt][reg] = ov; mi[mt][reg] = oi;
                }
            }
    }
    if (r16 == 0) {
#pragma unroll
        for (int mt = 0; mt < 2; ++mt)
#pragma unroll
            for (int reg = 0; reg < 4; ++reg)
                midx[mt*16 + g*4 + reg] = mi[mt][reg];
    }
    if (lane < 32) atomicAdd(&accg[1 + midx[lane]], 1.0f);

    // ---- z_q = z + (q - z) (bf16 z from zb, fp32 q), sse; coalesced stores
    float lsse = 0.f;
    {
        float4* zq4 = reinterpret_cast<float4*>(zq) + tb * 64;
        const float4* cf4 = reinterpret_cast<const float4*>(cbf);
#pragma unroll 1
        for (int it = 0; it < 32; ++it) {
            int slot = lane + it * 64;
            int t = slot >> 6, k4 = slot & 63;
            float4 q = cf4[(size_t)midx[t] * 64 + k4];
            ushort4 zu = *reinterpret_cast<const ushort4*>(&zb[t * CBLD + 4 * k4]);
            float zx = b2f(zu.x), zy = b2f(zu.y), zz = b2f(zu.z), zw = b2f(zu.w);
            float dx = q.x - zx, dy = q.y - zy, dz = q.z - zz, dw = q.w - zw;
            lsse += dx*dx + dy*dy + dz*dz + dw*dw;
            zq4[slot] = make_float4(zx + dx, zy + dy, zz + dz, zw + dw);
        }
    }
#pragma unroll
    for (int m = 1; m <= 32; m <<= 1) lsse += __shfl_xor(lsse, m);
    if (lane == 0) atomicAdd(&accg[0], lsse);

    // ---- decoder
    short8v aq[2][8];   // q rows bf16 from padded codebook (per-lane gather)
#pragma unroll
    for (int mt = 0; mt < 2; ++mt) {
        const ushort* qrow = cbbf + (size_t)midx[mt*16 + r16] * CBLD;
#pragma unroll
        for (int ks = 0; ks < 8; ++ks)
            aq[mt][ks] = *reinterpret_cast<const short8v*>(qrow + ks*32 + g*8);
    }
    dense_layer<8, 1>(wb + 49152, bb3, 8, aq, h3, 136, r16, g);     // d0 256->128
    short8v a3[2][4];
    read_afrags<4>(h3, 136, r16, g, a3);
    dense_layer<4, 1>(wb + 81920, bb4, 4, a3, h4, 72, r16, g);      // d1 128->64
    short8v a4[2][2];
    read_afrags<2>(h4, 72, r16, g, a4);

    // d2: 64 -> 128, sigmoid, direct global stores (C-layout)
    {
        const ushort* wD = wb + 90112;
        short8v cur[2], nxt[2];
        const ushort* wrow = wD + (size_t)r16 * 64 + g*8;
        cur[0] = *reinterpret_cast<const short8v*>(wrow);
        cur[1] = *reinterpret_cast<const short8v*>(wrow + 32);
        float bc = bb5[r16];
#pragma unroll 1
        for (int nt = 0; nt < 8; ++nt) {
            float bn = 0.f;
            if (nt + 1 < 8) {
                const ushort* wn = wrow + (size_t)(nt + 1) * 16 * 64;
                nxt[0] = *reinterpret_cast<const short8v*>(wn);
                nxt[1] = *reinterpret_cast<const short8v*>(wn + 32);
                bn = bb5[(nt + 1) * 16 + r16];
            }
#pragma unroll
            for (int mt = 0; mt < 2; ++mt) {
                float4v acc = (float4v){0.f,0.f,0.f,0.f};
                acc = __builtin_amdgcn_mfma_f32_16x16x32_bf16(a4[mt][0], cur[0], acc, 0, 0, 0);
                acc = __builtin_amdgcn_mfma_f32_16x16x32_bf16(a4[mt][1], cur[1], acc, 0, 0, 0);
#pragma unroll
                for (int reg = 0; reg < 4; ++reg) {
                    float v = acc[reg] + bc;
                    xr[(tb + mt*16 + g*4 + reg) * 128 + nt*16 + r16] =
                        1.0f / (1.0f + expf(-v));
                }
            }
            cur[0] = nxt[0]; cur[1] = nxt[1]; bc = bn;
        }
    }
}

// ================= finalize scalars =================
__global__ __launch_bounds__(512)
void finalize_kernel(const float* __restrict__ acc, float* __restrict__ out_scal)
{
    __shared__ float red[512];
    int tid = threadIdx.x;
    float p = acc[1 + tid] * (1.0f / (float)NTOK);
    red[tid] = p * logf(p + 1e-10f);
    __syncthreads();
    for (int s = 256; s > 0; s >>= 1) {
        if (tid < s) red[tid] += red[tid + s];
        __syncthreads();
    }
    if (tid == 0) {
        out_scal[0] = 1.25f * (acc[0] * (1.0f / 33554432.0f)); // q_latent + 0.25*e_latent
        out_scal[1] = expf(-red[0]);
    }
}

// ================= launch =================
extern "C" void kernel_launch(void* const* d_in, const int* in_sizes, int n_in,
                              void* d_out, int out_size, void* d_ws, size_t ws_size,
                              hipStream_t stream)
{
    (void)in_sizes; (void)n_in; (void)out_size; (void)ws_size;
    const float* x     = (const float*)d_in[0];
    const float* adapt = (const float*)d_in[1];
    const float* bw[6]  = {(const float*)d_in[2],  (const float*)d_in[6],  (const float*)d_in[10],
                           (const float*)d_in[14], (const float*)d_in[18], (const float*)d_in[22]};
    const float* bbp[6] = {(const float*)d_in[3],  (const float*)d_in[7],  (const float*)d_in[11],
                           (const float*)d_in[15], (const float*)d_in[19], (const float*)d_in[23]};
    const float* aw[6]  = {(const float*)d_in[4],  (const float*)d_in[8],  (const float*)d_in[12],
                           (const float*)d_in[16], (const float*)d_in[20], (const float*)d_in[24]};
    const float* ab[6]  = {(const float*)d_in[5],  (const float*)d_in[9],  (const float*)d_in[13],
                           (const float*)d_in[17], (const float*)d_in[21], (const float*)d_in[25]};
    const float* cb = (const float*)d_in[26];

    char*   wsb  = (char*)d_ws;
    ushort* wbf  = (ushort*)(wsb + WSB_W);
    ushort* cbbf = (ushort*)(wsb + WSB_CB);
    float*  cbn  = (float*) (wsb + WSB_CBN);
    float*  acc  = (float*) (wsb + WSB_ACC);

    float*  out  = (float*)d_out;
    float*  zf   = out;              // z_q fp32
    float*  scal = out + OUT_SCAL;
    float*  xr   = out + OUT_XR;     // x_recon fp32

    hipMemsetAsync(acc, 0, 513 * sizeof(float), stream);

    WgenP p;
    const int loff[6] = {0, 8192, 16384, 49152, 81920, 90112};
    for (int l = 0; l < 6; ++l) {
        p.bw[l] = bw[l]; p.aw[l] = aw[l]; p.ab[l] = ab[l]; p.loff[l] = loff[l];
    }

    prep_kernel<<<386, 256, 0, stream>>>(p, adapt, wbf, cb, cbn, cbbf);
    vqvae_fused<<<NTOK / 32, 64, 0, stream>>>(x, wbf,
                                              bbp[0], bbp[1], bbp[2], bbp[3], bbp[4], bbp[5],
                                              cbbf, cb, cbn, zf, xr, acc);
    finalize_kernel<<<1, 512, 0, stream>>>(acc, scal);
}